// Round 3
// baseline (734.941 us; speedup 1.0000x reference)
//
#include <hip/hip_runtime.h>
#include <hip/hip_cooperative_groups.h>
#include <math.h>

namespace cg = cooperative_groups;

#define HID 1024
#define VOCAB 32000
#define LAYERS 4
#define MAXLEN 128
#define SPAN 2

// d_out layout (floats): logp [0,64000) | hidden_new [64000,68096) | attn_w [68096,68224)
#define OUT_LOGP 0
#define OUT_HID 64000
#define OUT_ATTNW 68096

// ws layout (floats)
#define WS_XCAT 0       // 3072: emb(2048) | attn_applied(1024)
#define WS_SCORES 3072  // 128
#define WS_X 3200       // 1024 (comb output)
#define WS_RED 4352     // 512: per-block (max, sumexp)
#define WS_LOGITS 8192  // 64000

__device__ __forceinline__ float dot4(float4 a, float4 b) {
    return a.x * b.x + a.y * b.y + a.z * b.z + a.w * b.w;
}

__global__ __launch_bounds__(1024, 4) void mega(
    const int* __restrict__ ids,
    const float* __restrict__ hidden,
    const float* __restrict__ enc,
    const float* __restrict__ embedding,
    const float* __restrict__ attn_W,
    const float* __restrict__ attn_b,
    const float* __restrict__ comb_W,
    const float* __restrict__ comb_b,
    const float* __restrict__ gru_Wih,
    const float* __restrict__ gru_Whh,
    const float* __restrict__ gru_bih,
    const float* __restrict__ gru_bhh,
    const float* __restrict__ out_W,
    const float* __restrict__ out_b,
    float* __restrict__ out,
    float* __restrict__ ws)
{
    cg::grid_group grid = cg::this_grid();
    const int b = blockIdx.x;       // 0..255
    const int t = threadIdx.x;      // 0..1023
    const int wv = t >> 6;          // 0..15
    const int lane = t & 63;

    __shared__ float sred[16];
    __shared__ float ssum[16];
    __shared__ float w2[MAXLEN];
    __shared__ float part[8][MAXLEN];
    __shared__ float gdots[24];

    // ---- S1: attn scores (blocks 0..31, 4 waves per row) + emb gather (blocks 32..33)
    if (b < 32) {
        int gw = b * 16 + wv;            // 0..511
        int row = gw >> 2, q = gw & 3;   // row 0..127, quarter 0..3
        const float4* W4 = (const float4*)(attn_W + (size_t)row * 3072);
        float sum = 0.f;
#pragma unroll
        for (int i = 0; i < 3; i++) {
            int k4 = q * 192 + lane + 64 * i;   // 0..767
            float4 w = W4[k4];
            int e = k4 * 4;
            float4 x;
            if (e < 2048) {
                int r = ids[e >> 10];
                x = *(const float4*)(embedding + (size_t)r * HID + (e & 1023));
            } else {
                x = *(const float4*)(hidden + (e - 2048));   // hidden[0]
            }
            sum += dot4(w, x);
        }
        for (int o = 32; o > 0; o >>= 1) sum += __shfl_down(sum, o, 64);
        if (lane == 0) sred[wv] = sum;
        __syncthreads();
        if (t < 4) {
            int r = b * 4 + t;
            ws[WS_SCORES + r] = sred[4 * t] + sred[4 * t + 1] + sred[4 * t + 2] + sred[4 * t + 3] + attn_b[r];
        }
    } else if (b < 34) {
        int idx = (b - 32) * 1024 + t;   // 0..2047
        int r = ids[idx >> 10];
        ws[WS_XCAT + idx] = embedding[(size_t)r * HID + (idx & 1023)];
    }
    grid.sync();

    // ---- S2: softmax(128) + attn_applied (blocks 0..7, 128 cols each, 8 k-segs)
    if (b < 8) {
        if (t < 128) w2[t] = ws[WS_SCORES + t];
        __syncthreads();
        float m = -INFINITY;
        for (int k = 0; k < 128; k++) m = fmaxf(m, w2[k]);
        float s = 0.f;
        for (int k = 0; k < 128; k++) s += expf(w2[k] - m);
        __syncthreads();
        if (t < 128) w2[t] = expf(w2[t] - m) / s;
        __syncthreads();
        int col = b * 128 + (t & 127);
        int seg = t >> 7;
        float p = 0.f;
#pragma unroll
        for (int k = 0; k < 16; k++)
            p += w2[seg * 16 + k] * enc[(size_t)(seg * 16 + k) * HID + col];
        part[seg][t & 127] = p;
        __syncthreads();
        if (t < 128) {
            float acc = 0.f;
#pragma unroll
            for (int s2 = 0; s2 < 8; s2++) acc += part[s2][t];
            ws[WS_XCAT + 2048 + col] = acc;
            if (b == 0) out[OUT_ATTNW + t] = w2[t];
        }
    }
    grid.sync();

    // ---- S3: comb matvec + relu (all blocks, 4 rows/block, 4 waves/row)
    {
        int r0 = b * 4;
        int row = r0 + (wv & 3), q = wv >> 2;
        const float4* W4 = (const float4*)(comb_W + (size_t)row * 3072);
        const float4* x4 = (const float4*)(ws + WS_XCAT);
        float sum = 0.f;
#pragma unroll
        for (int i = 0; i < 3; i++) {
            int k4 = q * 192 + lane + 64 * i;
            sum += dot4(W4[k4], x4[k4]);
        }
        for (int o = 32; o > 0; o >>= 1) sum += __shfl_down(sum, o, 64);
        if (lane == 0) sred[wv] = sum;   // sred[q*4 + jloc]
        __syncthreads();
        if (t < 4) {
            float v = sred[t] + sred[t + 4] + sred[t + 8] + sred[t + 12] + comb_b[r0 + t];
            ws[WS_X + r0 + t] = fmaxf(v, 0.f);
        }
    }
    grid.sync();

    // ---- S4: GRU layers (all blocks, 4 j/block, 24 dots over 12 waves x 2)
    for (int l = 0; l < LAYERS; l++) {
        const float* inp = (l == 0) ? (ws + WS_X) : (out + OUT_HID + (l - 1) * HID);
        const float* h = hidden + (size_t)l * HID;
        const float* Wih = gru_Wih + (size_t)l * 3 * HID * HID;
        const float* Whh = gru_Whh + (size_t)l * 3 * HID * HID;
        const float* bih = gru_bih + (size_t)l * 3 * HID;
        const float* bhh = gru_bhh + (size_t)l * 3 * HID;
        int j0 = b * 4;
        if (wv < 12) {
            int da = 2 * wv, db = da + 1;
            int jla = da & 3, ga = da >> 2;
            int jlb = db & 3, gb = db >> 2;
            const float* Wra = (ga < 3) ? (Wih + ((size_t)ga * HID + j0 + jla) * HID)
                                        : (Whh + ((size_t)(ga - 3) * HID + j0 + jla) * HID);
            const float* Wrb = (gb < 3) ? (Wih + ((size_t)gb * HID + j0 + jlb) * HID)
                                        : (Whh + ((size_t)(gb - 3) * HID + j0 + jlb) * HID);
            const float4* xa4 = (const float4*)((ga < 3) ? inp : h);
            const float4* xb4 = (const float4*)((gb < 3) ? inp : h);
            const float4* Wa4 = (const float4*)Wra;
            const float4* Wb4 = (const float4*)Wrb;
            float sa = 0.f, sb = 0.f;
#pragma unroll
            for (int i = 0; i < 4; i++) {
                int k4 = lane + 64 * i;
                sa += dot4(Wa4[k4], xa4[k4]);
                sb += dot4(Wb4[k4], xb4[k4]);
            }
            for (int o = 32; o > 0; o >>= 1) {
                sa += __shfl_down(sa, o, 64);
                sb += __shfl_down(sb, o, 64);
            }
            if (lane == 0) { gdots[da] = sa; gdots[db] = sb; }
        }
        __syncthreads();
        if (t < 4) {
            int j = j0 + t;
            float ir = gdots[0 * 4 + t] + bih[j];
            float iz = gdots[1 * 4 + t] + bih[HID + j];
            float in_ = gdots[2 * 4 + t] + bih[2 * HID + j];
            float hr = gdots[3 * 4 + t] + bhh[j];
            float hz = gdots[4 * 4 + t] + bhh[HID + j];
            float hn = gdots[5 * 4 + t] + bhh[2 * HID + j];
            float rg = 1.f / (1.f + expf(-(ir + hr)));
            float zg = 1.f / (1.f + expf(-(iz + hz)));
            float ng = tanhf(in_ + rg * hn);
            out[OUT_HID + l * HID + j] = (1.f - zg) * ng + zg * h[j];
        }
        grid.sync();
    }

    // ---- S5: logits (250 rows/block) + per-block online logsumexp partials
    {
        int r0 = b * 250;
        const float4* x4 = (const float4*)(out + OUT_HID + 3 * HID);
        float4 xv[4];
#pragma unroll
        for (int i = 0; i < 4; i++) xv[i] = x4[lane + 64 * i];
        float m = -INFINITY, s = 0.f;
        for (int i = 0; i < 8; i++) {
            int oa = wv + 32 * i;
            int ob = oa + 16;
            bool vb = (ob < 250);          // wave-uniform
            int ra = r0 + oa;
            int rb = r0 + (vb ? ob : 0);
            const float4* Wa = (const float4*)(out_W + (size_t)ra * HID);
            const float4* Wb = (const float4*)(out_W + (size_t)rb * HID);
            float sa = 0.f, sb = 0.f;
            if (vb) {
#pragma unroll
                for (int k = 0; k < 4; k++) {
                    int k4 = lane + 64 * k;
                    sa += dot4(Wa[k4], xv[k]);
                    sb += dot4(Wb[k4], xv[k]);
                }
            } else {
#pragma unroll
                for (int k = 0; k < 4; k++) {
                    int k4 = lane + 64 * k;
                    sa += dot4(Wa[k4], xv[k]);
                }
            }
            for (int o = 32; o > 0; o >>= 1) {
                sa += __shfl_down(sa, o, 64);
                sb += __shfl_down(sb, o, 64);
            }
            if (lane == 0) {
                float v = sa + out_b[ra];
                ws[WS_LOGITS + ra] = v;
                if (v > m) { s = s * expf(m - v) + 1.f; m = v; } else { s += expf(v - m); }
                if (vb) {
                    float v2 = sb + out_b[rb];
                    ws[WS_LOGITS + rb] = v2;
                    if (v2 > m) { s = s * expf(m - v2) + 1.f; m = v2; } else { s += expf(v2 - m); }
                }
            }
        }
        if (lane == 0) { sred[wv] = m; ssum[wv] = s; }
        __syncthreads();
        if (t == 0) {
            float M = -INFINITY, S = 0.f;
            for (int k = 0; k < 16; k++) {
                float mk = sred[k], sk = ssum[k];
                if (mk > M) { S = S * expf(M - mk) + sk; M = mk; }
                else S += sk * expf(mk - M);
            }
            ws[WS_RED + b * 2] = M;
            ws[WS_RED + b * 2 + 1] = S;
        }
    }
    grid.sync();

    // ---- S6: combine 128 per-block partials per span, write logp
    {
        int span = b >> 7;
        float M = -INFINITY, S = 0.f;
        if (wv < 2) {
            // t in [0,128): one partial each (waves 0,1 fully covered)
            M = ws[WS_RED + span * 256 + t * 2];
            S = ws[WS_RED + span * 256 + t * 2 + 1];
            for (int o = 32; o > 0; o >>= 1) {
                float Mo = __shfl_down(M, o, 64);
                float So = __shfl_down(S, o, 64);
                float nM = fmaxf(M, Mo);
                S = S * expf(M - nM) + So * expf(Mo - nM);
                M = nM;
            }
            if (lane == 0) { sred[wv] = M; ssum[wv] = S; }
        }
        __syncthreads();
        float M0 = sred[0], S0 = ssum[0], M1 = sred[1], S1 = ssum[1];
        float gm = fmaxf(M0, M1);
        float lse = logf(S0 * expf(M0 - gm) + S1 * expf(M1 - gm));
        if (t < 250) {
            int i = b * 250 + t;
            out[OUT_LOGP + i] = ws[WS_LOGITS + i] - gm - lse;
        }
    }
}

extern "C" void kernel_launch(void* const* d_in, const int* in_sizes, int n_in,
                              void* d_out, int out_size, void* d_ws, size_t ws_size,
                              hipStream_t stream) {
    const int* ids = (const int*)d_in[0];
    const float* hidden = (const float*)d_in[1];
    const float* enc = (const float*)d_in[2];
    const float* embedding = (const float*)d_in[3];
    const float* attn_W = (const float*)d_in[4];
    const float* attn_b = (const float*)d_in[5];
    const float* comb_W = (const float*)d_in[6];
    const float* comb_b = (const float*)d_in[7];
    const float* gru_Wih = (const float*)d_in[8];
    const float* gru_Whh = (const float*)d_in[9];
    const float* gru_bih = (const float*)d_in[10];
    const float* gru_bhh = (const float*)d_in[11];
    const float* out_W = (const float*)d_in[12];
    const float* out_b = (const float*)d_in[13];
    float* out = (float*)d_out;
    float* ws = (float*)d_ws;

    void* kargs[] = {
        (void*)&ids, (void*)&hidden, (void*)&enc, (void*)&embedding,
        (void*)&attn_W, (void*)&attn_b, (void*)&comb_W, (void*)&comb_b,
        (void*)&gru_Wih, (void*)&gru_Whh, (void*)&gru_bih, (void*)&gru_bhh,
        (void*)&out_W, (void*)&out_b, (void*)&out, (void*)&ws
    };
    hipLaunchCooperativeKernel((void*)mega, dim3(256), dim3(1024), kargs, 0, stream);
}

// Round 4
// 511.119 us; speedup vs baseline: 1.4379x; 1.4379x over previous
//
#include <hip/hip_runtime.h>
#include <math.h>

#define HID 1024
#define VOCAB 32000
#define LAYERS 4
#define MAXLEN 128
#define SPAN 2

// d_out layout (floats): logp [0,64000) | hidden_new [64000,68096) | attn_w [68096,68224)
#define OUT_LOGP 0
#define OUT_HID 64000
#define OUT_ATTNW 68096

// ws layout (floats)
#define WS_XCAT 0       // 3072: emb(2048) | attn_applied(1024)
#define WS_SCORES 3072  // 128
#define WS_X 3200       // 1024 (comb output)
#define WS_GH 4224      // 12288: gh = Whh@h + bhh, all 4 layers
#define WS_RED 16512    // 4000: per-logits-block (max, sumexp)
#define WS_LOGITS 24576 // 64000

__device__ __forceinline__ float dot4(float4 a, float4 b) {
    return a.x * b.x + a.y * b.y + a.z * b.z + a.w * b.w;
}

// ---------- K1: attn scores + emb gather + GRU gh precompute ----------
// blocks 0..127: scores; 128..135: emb gather; 136..3207: gh rows (4/block).
__global__ __launch_bounds__(256) void k_pre(const int* __restrict__ ids,
                                             const float* __restrict__ hidden,
                                             const float* __restrict__ embedding,
                                             const float* __restrict__ attn_W,
                                             const float* __restrict__ attn_b,
                                             const float* __restrict__ gru_Whh,
                                             const float* __restrict__ gru_bhh,
                                             float* __restrict__ ws) {
    int b = blockIdx.x;
    int t = threadIdx.x;
    int lane = t & 63, wv = t >> 6;
    if (b < MAXLEN) {
        const float4* W4 = (const float4*)(attn_W + (size_t)b * 3072);
        float sum = 0.f;
#pragma unroll
        for (int i = 0; i < 3; i++) {
            int k4 = t + 256 * i;            // 0..767
            float4 w = W4[k4];
            int e = k4 * 4;
            float4 x;
            if (e < 2048) {
                int row = ids[e >> 10];
                x = *(const float4*)(embedding + (size_t)row * HID + (e & 1023));
            } else {
                x = *(const float4*)(hidden + (e - 2048));  // hidden[0]
            }
            sum += dot4(w, x);
        }
        __shared__ float sred[4];
        for (int o = 32; o > 0; o >>= 1) sum += __shfl_down(sum, o, 64);
        if (lane == 0) sred[wv] = sum;
        __syncthreads();
        if (t == 0) {
            float v = sred[0] + sred[1] + sred[2] + sred[3];
            ws[WS_SCORES + b] = v + attn_b[b];
        }
    } else if (b < MAXLEN + 8) {
        int idx = (b - MAXLEN) * 256 + t;    // 0..2047
        int row = ids[idx >> 10];
        ws[WS_XCAT + idx] = embedding[(size_t)row * HID + (idx & 1023)];
    } else {
        // gh precompute: r = global row in [0, 12288)
        int r = (b - MAXLEN - 8) * 4 + wv;
        int l = r / 3072;
        int g = r - l * 3072;
        const float4* W4 = (const float4*)(gru_Whh + ((size_t)l * 3072 + g) * HID);
        const float4* h4 = (const float4*)(hidden + (size_t)l * HID);
        float sum = 0.f;
#pragma unroll
        for (int i = 0; i < 4; i++) {
            int k4 = lane + 64 * i;
            sum += dot4(W4[k4], h4[k4]);
        }
        for (int o = 32; o > 0; o >>= 1) sum += __shfl_down(sum, o, 64);
        if (lane == 0) ws[WS_GH + r] = sum + gru_bhh[r];
    }
}

// ---------- K2: softmax(128) + attn_applied ----------
// grid 32 x 256. Block b: cols [b*32, b*32+32), 8 k-segments of 16.
__global__ __launch_bounds__(256) void k_softmax_apply(const float* __restrict__ enc,
                                                       float* __restrict__ ws,
                                                       float* __restrict__ out) {
    __shared__ float w2[MAXLEN];
    __shared__ float part[8][32];
    int t = threadIdx.x;
    if (t < 128) w2[t] = ws[WS_SCORES + t];
    __syncthreads();
    float m = -INFINITY;
    for (int k = 0; k < 128; k++) m = fmaxf(m, w2[k]);
    float s = 0.f;
    for (int k = 0; k < 128; k++) s += expf(w2[k] - m);
    __syncthreads();
    if (t < 128) {
        float wt = expf(w2[t] - m) / s;
        if (blockIdx.x == 0) out[OUT_ATTNW + t] = wt;
        w2[t] = wt;
    }
    __syncthreads();
    int col = blockIdx.x * 32 + (t & 31);
    int seg = t >> 5;
    float p = 0.f;
#pragma unroll
    for (int k = 0; k < 16; k++)
        p += w2[seg * 16 + k] * enc[(size_t)(seg * 16 + k) * HID + col];
    part[seg][t & 31] = p;
    __syncthreads();
    if (t < 32) {
        float acc = 0.f;
#pragma unroll
        for (int s2 = 0; s2 < 8; s2++) acc += part[s2][t];
        ws[WS_XCAT + 2048 + blockIdx.x * 32 + t] = acc;
    }
}

// ---------- K3: comb matvec + relu ----------
__global__ __launch_bounds__(256) void k_comb(const float* __restrict__ comb_W,
                                              const float* __restrict__ comb_b,
                                              float* __restrict__ ws) {
    int r = blockIdx.x, t = threadIdx.x;
    const float4* W4 = (const float4*)(comb_W + (size_t)r * 3072);
    const float4* x4 = (const float4*)(ws + WS_XCAT);
    float sum = 0.f;
#pragma unroll
    for (int i = 0; i < 3; i++) {
        int k4 = t + 256 * i;
        sum += dot4(W4[k4], x4[k4]);
    }
    __shared__ float sred[4];
    int lane = t & 63, wid = t >> 6;
    for (int o = 32; o > 0; o >>= 1) sum += __shfl_down(sum, o, 64);
    if (lane == 0) sred[wid] = sum;
    __syncthreads();
    if (t == 0) {
        float v = sred[0] + sred[1] + sred[2] + sred[3];
        ws[WS_X + r] = fmaxf(v + comb_b[r], 0.f);
    }
}

// ---------- K4..K7: GRU layer (gh precomputed) ----------
// grid 1024 x 192 (3 waves = gates r,z,n of unit j).
__global__ __launch_bounds__(192) void k_gru(const float* __restrict__ inp,
                                             const float* __restrict__ h,
                                             const float* __restrict__ Wih,
                                             const float* __restrict__ bih,
                                             const float* __restrict__ gh,
                                             float* __restrict__ h_out) {
    int j = blockIdx.x;
    int t = threadIdx.x;
    int wv = t >> 6, lane = t & 63;
    __shared__ float dots[3];
    const float4* W4 = (const float4*)(Wih + ((size_t)wv * HID + j) * HID);
    const float4* x4 = (const float4*)inp;
    float sum = 0.f;
#pragma unroll
    for (int i = 0; i < 4; i++) {
        int k4 = lane + 64 * i;
        sum += dot4(W4[k4], x4[k4]);
    }
    for (int o = 32; o > 0; o >>= 1) sum += __shfl_down(sum, o, 64);
    if (lane == 0) dots[wv] = sum;
    __syncthreads();
    if (t == 0) {
        float ir = dots[0] + bih[j];
        float iz = dots[1] + bih[HID + j];
        float in_ = dots[2] + bih[2 * HID + j];
        float hr = gh[j];
        float hz = gh[HID + j];
        float hn = gh[2 * HID + j];
        float rg = 1.f / (1.f + expf(-(ir + hr)));
        float zg = 1.f / (1.f + expf(-(iz + hz)));
        float ng = tanhf(in_ + rg * hn);
        h_out[j] = (1.f - zg) * ng + zg * h[j];
    }
}

// ---------- K8: logits + per-block online LSE partial ----------
// grid 2000 x 256 (4 waves), 8 rows/wave.
__global__ __launch_bounds__(256) void k_logits(const float* __restrict__ h3,
                                                const float* __restrict__ out_W,
                                                const float* __restrict__ out_b,
                                                float* __restrict__ ws) {
    int wv = threadIdx.x >> 6, lane = threadIdx.x & 63;
    int r0 = blockIdx.x * 32 + wv * 8;
    const float4* x4 = (const float4*)h3;
    float4 xv[4];
#pragma unroll
    for (int i = 0; i < 4; i++) xv[i] = x4[lane + 64 * i];
    const float4* W4 = (const float4*)(out_W + (size_t)r0 * HID);
    float s[8];
#pragma unroll
    for (int r = 0; r < 8; r++) {
        s[r] = 0.f;
#pragma unroll
        for (int k = 0; k < 4; k++)
            s[r] += dot4(W4[r * 256 + lane + 64 * k], xv[k]);
    }
#pragma unroll
    for (int r = 0; r < 8; r++)
        for (int o = 32; o > 0; o >>= 1) s[r] += __shfl_down(s[r], o, 64);
    __shared__ float sm[4], ss[4];
    if (lane == 0) {
        float4 b0 = *(const float4*)(out_b + r0);
        float4 b1 = *(const float4*)(out_b + r0 + 4);
        float v0 = s[0] + b0.x, v1 = s[1] + b0.y, v2 = s[2] + b0.z, v3 = s[3] + b0.w;
        float v4 = s[4] + b1.x, v5 = s[5] + b1.y, v6 = s[6] + b1.z, v7 = s[7] + b1.w;
        *(float4*)(ws + WS_LOGITS + r0) = make_float4(v0, v1, v2, v3);
        *(float4*)(ws + WS_LOGITS + r0 + 4) = make_float4(v4, v5, v6, v7);
        float vv[8] = {v0, v1, v2, v3, v4, v5, v6, v7};
        float M = vv[0], S = 1.f;
#pragma unroll
        for (int r = 1; r < 8; r++) {
            float v = vv[r];
            if (v > M) { S = S * expf(M - v) + 1.f; M = v; }
            else S += expf(v - M);
        }
        sm[wv] = M; ss[wv] = S;
    }
    __syncthreads();
    if (threadIdx.x == 0) {
        float M = sm[0], S = ss[0];
#pragma unroll
        for (int k = 1; k < 4; k++) {
            float mk = sm[k], sk = ss[k];
            if (mk > M) { S = S * expf(M - mk) + sk; M = mk; }
            else S += sk * expf(mk - M);
        }
        ws[WS_RED + blockIdx.x * 2] = M;
        ws[WS_RED + blockIdx.x * 2 + 1] = S;
    }
}

// ---------- K9: combine partials + logp write ----------
// grid 250 x 256; 1000 partials per span (125 blocks per span).
__global__ __launch_bounds__(256) void k_logp(const float* __restrict__ ws,
                                              float* __restrict__ out) {
    int t = threadIdx.x, b = blockIdx.x;
    int span = b / 125;
    int lane = t & 63, wv = t >> 6;
    __shared__ float sm[4], ss[4];
    __shared__ float gm_s, ls_s;
    float M = -INFINITY, S = 0.f;
#pragma unroll
    for (int k = 0; k < 4; k++) {
        int p = t + 256 * k;
        if (p < 1000) {
            float mk = ws[WS_RED + (span * 1000 + p) * 2];
            float sk = ws[WS_RED + (span * 1000 + p) * 2 + 1];
            if (mk > M) { S = S * expf(M - mk) + sk; M = mk; }
            else S += sk * expf(mk - M);
        }
    }
    for (int o = 32; o > 0; o >>= 1) {
        float Mo = __shfl_down(M, o, 64);
        float So = __shfl_down(S, o, 64);
        float nM = fmaxf(M, Mo);
        S = S * expf(M - nM) + So * expf(Mo - nM);
        M = nM;
    }
    if (lane == 0) { sm[wv] = M; ss[wv] = S; }
    __syncthreads();
    if (t == 0) {
        float Mf = sm[0], Sf = ss[0];
#pragma unroll
        for (int k = 1; k < 4; k++) {
            float mk = sm[k], sk = ss[k];
            if (mk > Mf) { Sf = Sf * expf(Mf - mk) + sk; Mf = mk; }
            else Sf += sk * expf(mk - Mf);
        }
        gm_s = Mf; ls_s = logf(Sf);
    }
    __syncthreads();
    int i = b * 256 + t;
    out[OUT_LOGP + i] = ws[WS_LOGITS + i] - gm_s - ls_s;
}

extern "C" void kernel_launch(void* const* d_in, const int* in_sizes, int n_in,
                              void* d_out, int out_size, void* d_ws, size_t ws_size,
                              hipStream_t stream) {
    const int* ids = (const int*)d_in[0];
    const float* hidden = (const float*)d_in[1];
    const float* enc = (const float*)d_in[2];
    const float* embedding = (const float*)d_in[3];
    const float* attn_W = (const float*)d_in[4];
    const float* attn_b = (const float*)d_in[5];
    const float* comb_W = (const float*)d_in[6];
    const float* comb_b = (const float*)d_in[7];
    const float* gru_Wih = (const float*)d_in[8];
    const float* gru_Whh = (const float*)d_in[9];
    const float* gru_bih = (const float*)d_in[10];
    const float* gru_bhh = (const float*)d_in[11];
    const float* out_W = (const float*)d_in[12];
    const float* out_b = (const float*)d_in[13];
    float* out = (float*)d_out;
    float* ws = (float*)d_ws;

    k_pre<<<3208, 256, 0, stream>>>(ids, hidden, embedding, attn_W, attn_b,
                                    gru_Whh, gru_bhh, ws);
    k_softmax_apply<<<32, 256, 0, stream>>>(enc, ws, out);
    k_comb<<<1024, 256, 0, stream>>>(comb_W, comb_b, ws);
    for (int l = 0; l < LAYERS; l++) {
        const float* inp = (l == 0) ? (ws + WS_X) : (out + OUT_HID + (l - 1) * HID);
        k_gru<<<1024, 192, 0, stream>>>(inp,
                                        hidden + (size_t)l * HID,
                                        gru_Wih + (size_t)l * 3 * HID * HID,
                                        gru_bih + (size_t)l * 3 * HID,
                                        ws + WS_GH + (size_t)l * 3 * HID,
                                        out + OUT_HID + l * HID);
    }
    k_logits<<<2000, 256, 0, stream>>>(out + OUT_HID + 3 * HID, out_W, out_b, ws);
    k_logp<<<250, 256, 0, stream>>>(ws, out);
}